// Round 2
// baseline (1602.838 us; speedup 1.0000x reference)
//
#include <hip/hip_runtime.h>
#include <hip/hip_bf16.h>

#define N_FULL 200000
#define N_SUB  80000
#define E_NUM  800000
#define IN_DIM 128
#define HD     128
#define LMAX   5

#define NB_SCAN ((N_SUB + 255) / 256)   // 313

// ---------------- init + CSR build ----------------

__global__ void init_all(int* __restrict__ cnt, int* __restrict__ cursor,
                         int* __restrict__ level, int* __restrict__ lvlcnt,
                         int* __restrict__ lvlcur) {
    int i = blockIdx.x * blockDim.x + threadIdx.x;
    if (i < N_SUB) {
        cnt[i] = 0;
        cursor[i] = 0;
        level[i] = (i < 2) ? 0 : 7;
    }
    if (i < 16) { lvlcnt[i] = 0; lvlcur[i] = 0; }
}

__global__ void count_deg(const int* __restrict__ dst, int* __restrict__ cnt) {
    int i = blockIdx.x * blockDim.x + threadIdx.x;
    if (i < E_NUM) atomicAdd(&cnt[dst[i]], 1);
}

__global__ void scan_block(const int* __restrict__ cnt, int* __restrict__ offs,
                           int* __restrict__ bsums) {
    __shared__ int s[256];
    int t = threadIdx.x;
    int i = blockIdx.x * 256 + t;
    int v = (i < N_SUB) ? cnt[i] : 0;
    s[t] = v;
    __syncthreads();
    for (int off = 1; off < 256; off <<= 1) {
        int x = (t >= off) ? s[t - off] : 0;
        __syncthreads();
        s[t] += x;
        __syncthreads();
    }
    if (i < N_SUB) offs[i] = s[t] - v;
    if (t == 255) bsums[blockIdx.x] = s[255];
}

__global__ void scan_sums(int* __restrict__ bsums) {
    __shared__ int s[512];
    int t = threadIdx.x;
    int v = (t < NB_SCAN) ? bsums[t] : 0;
    s[t] = v;
    __syncthreads();
    for (int off = 1; off < 512; off <<= 1) {
        int x = (t >= off) ? s[t - off] : 0;
        __syncthreads();
        s[t] += x;
        __syncthreads();
    }
    if (t < NB_SCAN) bsums[t] = s[t] - v;
}

__global__ void scan_add(int* __restrict__ offs, const int* __restrict__ bsums) {
    int i = blockIdx.x * 256 + threadIdx.x;
    if (i < N_SUB) offs[i] += bsums[blockIdx.x];
    if (i == 0) offs[N_SUB] = E_NUM;
}

__global__ void fill_csr(const int* __restrict__ src, const int* __restrict__ dst,
                         const int* __restrict__ offs, int* __restrict__ cursor,
                         int* __restrict__ csr) {
    int i = blockIdx.x * blockDim.x + threadIdx.x;
    if (i < E_NUM) {
        int d = dst[i];
        int p = atomicAdd(&cursor[d], 1);
        csr[offs[d] + p] = src[i];
    }
}

// ---------------- reverse BFS from {0,1}: level[u] = dist ----------------
// pass t: for edge u->v with level[v]==t, set level[u]=t+1 if unvisited.
// Benign race: all writers in a pass write the same value t+1.

__global__ void bfs_pass(const int* __restrict__ src, const int* __restrict__ dst,
                         int* __restrict__ level, int t) {
    int i = blockIdx.x * blockDim.x + threadIdx.x;
    if (i >= E_NUM) return;
    int v = dst[i];
    if (level[v] == t) {
        int u = src[i];
        if (level[u] > t + 1) level[u] = t + 1;
    }
}

__global__ void count_levels(const int* __restrict__ level, int* __restrict__ lvlcnt) {
    int i = blockIdx.x * blockDim.x + threadIdx.x;
    if (i < N_SUB) {
        int l = level[i];
        if (l <= 5) atomicAdd(&lvlcnt[l], 1);
    }
}

// base[l] = start offset of level l in order[]; cum[t] = |C_t| = #nodes with level<=t
__global__ void scan_levels(const int* __restrict__ lvlcnt, int* __restrict__ base,
                            int* __restrict__ cum) {
    if (threadIdx.x == 0 && blockIdx.x == 0) {
        int acc = 0;
        for (int l = 0; l <= 5; ++l) {
            base[l] = acc;
            acc += lvlcnt[l];
            cum[l] = acc;
        }
    }
}

__global__ void append_levels(const int* __restrict__ level, const int* __restrict__ base,
                              int* __restrict__ lvlcur, int* __restrict__ order) {
    int i = blockIdx.x * blockDim.x + threadIdx.x;
    if (i < N_SUB) {
        int l = level[i];
        if (l <= 5) {
            int p = base[l] + atomicAdd(&lvlcur[l], 1);
            order[p] = i;
        }
    }
}

// ---------------- mean aggregation over node list ----------------

__global__ __launch_bounds__(256) void aggregate_list(
    const float* __restrict__ H, float* __restrict__ Out,
    const int* __restrict__ offs, const int* __restrict__ csr,
    const int* __restrict__ cnt, const int* __restrict__ order,
    const int* __restrict__ cumptr, int lvl) {
    int M = cumptr[lvl];
    int ngroups = (M + 3) >> 2;
    int wid = threadIdx.x >> 6, lane = threadIdx.x & 63;
    for (int g = blockIdx.x; g < ngroups; g += gridDim.x) {
        int ni = g * 4 + wid;
        if (ni >= M) continue;
        int node = order[ni];
        int beg = offs[node], end = offs[node + 1];
        float ax = 0.f, ay = 0.f;
        for (int j = beg; j < end; ++j) {
            int s = csr[j];
            float2 v = *(const float2*)(H + (size_t)s * HD + lane * 2);
            ax += v.x; ay += v.y;
        }
        int c = cnt[node];
        float inv = 1.0f / (float)(c > 1 ? c : 1);
        *(float2*)(Out + (size_t)node * HD + lane * 2) = make_float2(ax * inv, ay * inv);
    }
}

// ---------------- fp32 tiled GEMM over node list (grid-stride) ----------------
// For rows i < M = cumptr[lvl]: nr = order[i];  ar = gather ? gather[nr] : nr
// Out[nr][:] = act( A1[ar] @ W1.T (+ A2[ar] @ W2.T) + bias )

#define GBM 64
#define GBK 32

__global__ __launch_bounds__(256) void gemm_list(
    const float* __restrict__ A1, const float* __restrict__ A2,
    const float* __restrict__ W1, const float* __restrict__ W2,
    const float* __restrict__ bias, float* __restrict__ Out,
    const int* __restrict__ order, const int* __restrict__ gather,
    const int* __restrict__ cumptr, int lvl, int do_relu) {

    __shared__ __align__(16) float As[GBK][68];
    __shared__ __align__(16) float Ws[GBK][132];

    int M = cumptr[lvl];
    int ntiles = (M + GBM - 1) / GBM;
    int tid = threadIdx.x;
    int tx = tid & 15, ty = tid >> 4;
    int r0 = ty * 4;
    int c0 = tx * 4;
    int nchunk = A2 ? 8 : 4;

    for (int tile = blockIdx.x; tile < ntiles; tile += gridDim.x) {
        int row0 = tile * GBM;

        float acc[4][8];
#pragma unroll
        for (int i = 0; i < 4; ++i)
#pragma unroll
            for (int j = 0; j < 8; ++j) acc[i][j] = 0.f;

        for (int ch = 0; ch < nchunk; ++ch) {
            const float* Asrc = (ch < 4) ? A1 : A2;
            const float* Wsrc = (ch < 4) ? W1 : W2;
            int kbase = (ch & 3) * GBK;

#pragma unroll
            for (int it = 0; it < 2; ++it) {
                int idx = tid + it * 256;
                int m = idx >> 3, kq = idx & 7;
                int row = row0 + m;
                float4 v = make_float4(0.f, 0.f, 0.f, 0.f);
                if (row < M) {
                    int nr = order[row];
                    int ar = gather ? gather[nr] : nr;
                    v = *(const float4*)(Asrc + (size_t)ar * 128 + kbase + kq * 4);
                }
                As[kq * 4 + 0][m] = v.x;
                As[kq * 4 + 1][m] = v.y;
                As[kq * 4 + 2][m] = v.z;
                As[kq * 4 + 3][m] = v.w;
            }
#pragma unroll
            for (int it = 0; it < 4; ++it) {
                int idx = tid + it * 256;
                int n = idx >> 3, kq = idx & 7;
                float4 v = *(const float4*)(Wsrc + n * 128 + kbase + kq * 4);
                Ws[kq * 4 + 0][n] = v.x;
                Ws[kq * 4 + 1][n] = v.y;
                Ws[kq * 4 + 2][n] = v.z;
                Ws[kq * 4 + 3][n] = v.w;
            }
            __syncthreads();

#pragma unroll
            for (int kk = 0; kk < GBK; ++kk) {
                float4 a  = *(const float4*)&As[kk][r0];
                float4 w0 = *(const float4*)&Ws[kk][c0];
                float4 w1 = *(const float4*)&Ws[kk][c0 + 64];
                float av[4] = {a.x, a.y, a.z, a.w};
                float wv[8] = {w0.x, w0.y, w0.z, w0.w, w1.x, w1.y, w1.z, w1.w};
#pragma unroll
                for (int i = 0; i < 4; ++i)
#pragma unroll
                    for (int j = 0; j < 8; ++j)
                        acc[i][j] = fmaf(av[i], wv[j], acc[i][j]);
            }
            __syncthreads();
        }

#pragma unroll
        for (int i = 0; i < 4; ++i) {
            int row = row0 + r0 + i;
            if (row >= M) continue;
            int nr = order[row];
            float4 o0, o1;
            o0.x = acc[i][0] + bias[c0 + 0];
            o0.y = acc[i][1] + bias[c0 + 1];
            o0.z = acc[i][2] + bias[c0 + 2];
            o0.w = acc[i][3] + bias[c0 + 3];
            o1.x = acc[i][4] + bias[c0 + 64];
            o1.y = acc[i][5] + bias[c0 + 65];
            o1.z = acc[i][6] + bias[c0 + 66];
            o1.w = acc[i][7] + bias[c0 + 67];
            if (do_relu) {
                o0.x = fmaxf(o0.x, 0.f); o0.y = fmaxf(o0.y, 0.f);
                o0.z = fmaxf(o0.z, 0.f); o0.w = fmaxf(o0.w, 0.f);
                o1.x = fmaxf(o1.x, 0.f); o1.y = fmaxf(o1.y, 0.f);
                o1.z = fmaxf(o1.z, 0.f); o1.w = fmaxf(o1.w, 0.f);
            }
            *(float4*)(Out + (size_t)nr * 128 + c0) = o0;
            *(float4*)(Out + (size_t)nr * 128 + c0 + 64) = o1;
        }
    }
}

// ---------------- head MLP on nodes 0,1 ----------------

__global__ void head_kernel(const float* __restrict__ H,
                            const float* __restrict__ W_e1, const float* __restrict__ b_e1,
                            const float* __restrict__ W_e2, const float* __restrict__ b_e2,
                            const float* __restrict__ W_h1, const float* __restrict__ b_h1,
                            const float* __restrict__ W_h2, const float* __restrict__ b_h2,
                            float* __restrict__ head_out, int kidx) {
    __shared__ float hu[128], hv[128], red[2];
    __shared__ float sc_sh;
    int t = threadIdx.x;
    hu[t] = H[t];
    hv[t] = H[128 + t];
    __syncthreads();

    float accv = b_e1[t];
    const float* wr = W_e1 + t * 384;
    for (int k2 = 0; k2 < 128; ++k2) {
        float a = hu[k2], b = hv[k2];
        accv += a * wr[k2] + b * wr[128 + k2] + a * b * wr[256 + k2];
    }
    float v = fmaxf(accv, 0.f) * W_e2[t];
    for (int off = 32; off; off >>= 1) v += __shfl_down(v, off);
    if ((t & 63) == 0) red[t >> 6] = v;
    __syncthreads();
    if (t == 0) sc_sh = red[0] + red[1] + b_e2[0];
    __syncthreads();
    float score = sc_sh;

    if (t < 64) {
        float a2 = b_h1[t];
        const float* wh = W_h1 + t * 257;
        for (int k2 = 0; k2 < 128; ++k2)
            a2 += hu[k2] * wh[k2] + hv[k2] * wh[128 + k2];
        a2 += score * wh[256];
        float g = fmaxf(a2, 0.f) * W_h2[t];
        for (int off = 32; off; off >>= 1) g += __shfl_down(g, off);
        if (t == 0) {
            float p = 1.f / (1.f + expf(-(g + b_h2[0])));
            head_out[kidx * 2 + 0] = score;
            head_out[kidx * 2 + 1] = p;
        }
    }
}

__global__ void finalize(const float* __restrict__ head_out, float* __restrict__ out) {
    if (threadIdx.x == 0 && blockIdx.x == 0) {
        float a[LMAX];
        float p_not = 1.f, s = 0.f;
        for (int k = 0; k < LMAX; ++k) {
            float p = head_out[2 * k + 1];
            a[k] = p * p_not;
            p_not *= (1.f - p);
            s += a[k];
        }
        float inv = 1.f / (s + 1e-8f);
        float fs = 0.f, ed = 0.f;
        for (int k = 0; k < LMAX; ++k) {
            float al = a[k] * inv;
            out[2 + k] = al;
            fs += al * head_out[2 * k];
            ed += al * (float)(k + 1);
        }
        out[0] = fs;
        out[1] = ed;
    }
}

// ---------------- launch ----------------

extern "C" void kernel_launch(void* const* d_in, const int* in_sizes, int n_in,
                              void* d_out, int out_size, void* d_ws, size_t ws_size,
                              hipStream_t stream) {
    const float* x_full = (const float*)d_in[0];
    const float* W_in  = (const float*)d_in[1];
    const float* b_in  = (const float*)d_in[2];
    const float* W_l   = (const float*)d_in[3];
    const float* b_l   = (const float*)d_in[4];
    const float* W_r   = (const float*)d_in[5];
    const float* W_e1  = (const float*)d_in[6];
    const float* b_e1  = (const float*)d_in[7];
    const float* W_e2  = (const float*)d_in[8];
    const float* b_e2  = (const float*)d_in[9];
    const float* W_h1  = (const float*)d_in[10];
    const float* b_h1  = (const float*)d_in[11];
    const float* W_h2  = (const float*)d_in[12];
    const float* b_h2  = (const float*)d_in[13];
    const int* subset  = (const int*)d_in[14];
    const int* edge    = (const int*)d_in[15];
    const int* esrc = edge;
    const int* edst = edge + E_NUM;

    // workspace carve-up
    char* w = (char*)d_ws;
    float* HA = (float*)w;      w += (size_t)N_SUB * HD * 4;   // 40.96 MB
    float* HB = (float*)w;      w += (size_t)N_SUB * HD * 4;   // 40.96 MB
    int* cnt = (int*)w;         w += (size_t)N_SUB * 4;
    int* offs = (int*)w;        w += (size_t)(N_SUB + 64) * 4;
    int* cursor = (int*)w;      w += (size_t)N_SUB * 4;
    int* csr = (int*)w;         w += (size_t)E_NUM * 4;        // 3.2 MB
    int* level = (int*)w;       w += (size_t)N_SUB * 4;
    int* order = (int*)w;       w += (size_t)N_SUB * 4;
    int* bsums = (int*)w;       w += 4096;
    int* lvlcnt = (int*)w;      w += 64;
    int* lvlbase = (int*)w;     w += 64;
    int* lvlcur = (int*)w;      w += 64;
    int* cum = (int*)w;         w += 64;
    float* head_out = (float*)w; w += 256;

    // init + CSR build
    init_all<<<NB_SCAN, 256, 0, stream>>>(cnt, cursor, level, lvlcnt, lvlcur);
    count_deg<<<(E_NUM + 255) / 256, 256, 0, stream>>>(edst, cnt);
    scan_block<<<NB_SCAN, 256, 0, stream>>>(cnt, offs, bsums);
    scan_sums<<<1, 512, 0, stream>>>(bsums);
    scan_add<<<NB_SCAN, 256, 0, stream>>>(offs, bsums);
    fill_csr<<<(E_NUM + 255) / 256, 256, 0, stream>>>(esrc, edst, offs, cursor, csr);

    // reverse BFS levels from {0,1}
    for (int t = 0; t < 5; ++t)
        bfs_pass<<<(E_NUM + 255) / 256, 256, 0, stream>>>(esrc, edst, level, t);
    count_levels<<<NB_SCAN, 256, 0, stream>>>(level, lvlcnt);
    scan_levels<<<1, 1, 0, stream>>>(lvlcnt, lvlbase, cum);
    append_levels<<<NB_SCAN, 256, 0, stream>>>(level, lvlbase, lvlcur, order);

    // input projection on C_5: HA[nr] = x_full[subset[nr]] @ W_in.T + b_in
    gemm_list<<<1250, 256, 0, stream>>>(
        x_full, nullptr, W_in, nullptr, b_in, HA, order, subset, cum, 5, 0);

    for (int k = 1; k <= LMAX; ++k) {
        int lvl = LMAX - k;                   // compute on C_{5-k}
        int agrid  = (k == 1) ? 2048 : 96;
        int ggrid  = (k == 1) ? 640  : 96;
        aggregate_list<<<agrid, 256, 0, stream>>>(HA, HB, offs, csr, cnt, order, cum, lvl);
        gemm_list<<<ggrid, 256, 0, stream>>>(
            HB, HA, W_l, W_r, b_l, HA, order, nullptr, cum, lvl, 1);
        head_kernel<<<1, 128, 0, stream>>>(HA, W_e1, b_e1, W_e2, b_e2,
                                           W_h1, b_h1, W_h2, b_h2, head_out, k - 1);
    }
    finalize<<<1, 1, 0, stream>>>(head_out, (float*)d_out);
}

// Round 3
// 478.594 us; speedup vs baseline: 3.3491x; 3.3491x over previous
//
#include <hip/hip_runtime.h>
#include <hip/hip_bf16.h>

#define N_FULL 200000
#define N_SUB  80000
#define E_NUM  800000
#define IN_DIM 128
#define HD     128
#define LMAX   5

#define NB_SCAN ((N_SUB + 255) / 256)   // 313

// ---------------- init + CSR build ----------------

__global__ void init_all(int* __restrict__ cnt, int* __restrict__ cursor,
                         int* __restrict__ level) {
    int i = blockIdx.x * blockDim.x + threadIdx.x;
    if (i < N_SUB) {
        cnt[i] = 0;
        cursor[i] = 0;
        level[i] = (i < 2) ? 0 : 7;
    }
}

__global__ void count_deg(const int* __restrict__ dst, int* __restrict__ cnt) {
    int i = blockIdx.x * blockDim.x + threadIdx.x;
    if (i < E_NUM) atomicAdd(&cnt[dst[i]], 1);
}

__global__ void scan_block(const int* __restrict__ cnt, int* __restrict__ offs,
                           int* __restrict__ bsums) {
    __shared__ int s[256];
    int t = threadIdx.x;
    int i = blockIdx.x * 256 + t;
    int v = (i < N_SUB) ? cnt[i] : 0;
    s[t] = v;
    __syncthreads();
    for (int off = 1; off < 256; off <<= 1) {
        int x = (t >= off) ? s[t - off] : 0;
        __syncthreads();
        s[t] += x;
        __syncthreads();
    }
    if (i < N_SUB) offs[i] = s[t] - v;
    if (t == 255) bsums[blockIdx.x] = s[255];
}

__global__ void scan_sums(int* __restrict__ bsums) {
    __shared__ int s[512];
    int t = threadIdx.x;
    int v = (t < NB_SCAN) ? bsums[t] : 0;
    s[t] = v;
    __syncthreads();
    for (int off = 1; off < 512; off <<= 1) {
        int x = (t >= off) ? s[t - off] : 0;
        __syncthreads();
        s[t] += x;
        __syncthreads();
    }
    if (t < NB_SCAN) bsums[t] = s[t] - v;
}

__global__ void scan_add(int* __restrict__ offs, const int* __restrict__ bsums) {
    int i = blockIdx.x * 256 + threadIdx.x;
    if (i < N_SUB) offs[i] += bsums[blockIdx.x];
    if (i == 0) offs[N_SUB] = E_NUM;
}

__global__ void fill_csr(const int* __restrict__ src, const int* __restrict__ dst,
                         const int* __restrict__ offs, int* __restrict__ cursor,
                         int* __restrict__ csr) {
    int i = blockIdx.x * blockDim.x + threadIdx.x;
    if (i < E_NUM) {
        int d = dst[i];
        int p = atomicAdd(&cursor[d], 1);
        csr[offs[d] + p] = src[i];
    }
}

// ---------------- reverse BFS from {0,1}: level[u] = dist ----------------
// pass t: for edge u->v with level[v]==t, set level[u]=t+1 if unvisited.
// Benign race: all writers in a pass write the same value t+1.

__global__ void bfs_pass(const int* __restrict__ src, const int* __restrict__ dst,
                         int* __restrict__ level, int t) {
    int i = blockIdx.x * blockDim.x + threadIdx.x;
    if (i >= E_NUM) return;
    int v = dst[i];
    if (level[v] == t) {
        int u = src[i];
        if (level[u] > t + 1) level[u] = t + 1;
    }
}

// ---------------- level compaction (no global atomics) ----------------
// A: per-block LDS histogram of levels

__global__ __launch_bounds__(256) void hist_levels(const int* __restrict__ level,
                                                   int* __restrict__ bhist) {
    __shared__ int h[8];
    int t = threadIdx.x;
    if (t < 8) h[t] = 0;
    __syncthreads();
    int i = blockIdx.x * 256 + t;
    if (i < N_SUB) {
        int l = level[i];
        if (l > 5) l = 6;
        atomicAdd(&h[l], 1);   // LDS atomic, per-block only
    }
    __syncthreads();
    if (t < 8) bhist[blockIdx.x * 8 + t] = h[t];
}

// B: per-level exclusive prefix over block histograms (in-place) + base/cum

__global__ void scan_hist(int* __restrict__ bhist, int* __restrict__ base,
                          int* __restrict__ cum) {
    __shared__ int tot[8];
    int t = threadIdx.x;
    if (t < 8) {
        int acc = 0;
        for (int b = 0; b < NB_SCAN; ++b) {
            int v = bhist[b * 8 + t];
            bhist[b * 8 + t] = acc;
            acc += v;
        }
        tot[t] = acc;
    }
    __syncthreads();
    if (t == 0) {
        int acc = 0;
        for (int l = 0; l <= 5; ++l) {
            base[l] = acc;
            acc += tot[l];
            cum[l] = acc;
        }
    }
}

// C: scatter nodes into order[] grouped by level, stable, no atomics

__global__ __launch_bounds__(256) void emit_order(const int* __restrict__ level,
                                                  const int* __restrict__ bhist,
                                                  const int* __restrict__ base,
                                                  int* __restrict__ order) {
    __shared__ int woff[4][8];
    int t = threadIdx.x;
    int lane = t & 63, wv = t >> 6;
    int i = blockIdx.x * 256 + t;
    int l = 7;
    if (i < N_SUB) {
        l = level[i];
        if (l > 5) l = 6;
    }
    unsigned long long mybal = 0;
#pragma unroll
    for (int q = 0; q < 8; ++q) {
        unsigned long long b = __ballot(l == q);
        if (q == l) mybal = b;
        if (lane == 0) woff[wv][q] = (int)__popcll(b);
    }
    int inrank = (int)__popcll(mybal & ((1ull << lane) - 1ull));
    __syncthreads();
    if (t < 8) {
        int acc = 0;
        for (int w2 = 0; w2 < 4; ++w2) {
            int c = woff[w2][t];
            woff[w2][t] = acc;
            acc += c;
        }
    }
    __syncthreads();
    if (i < N_SUB && l <= 5) {
        int pos = base[l] + bhist[blockIdx.x * 8 + l] + woff[wv][l] + inrank;
        order[pos] = i;
    }
}

// ---------------- mean aggregation over node list ----------------

__global__ __launch_bounds__(256) void aggregate_list(
    const float* __restrict__ H, float* __restrict__ Out,
    const int* __restrict__ offs, const int* __restrict__ csr,
    const int* __restrict__ cnt, const int* __restrict__ order,
    const int* __restrict__ cumptr, int lvl) {
    int M = cumptr[lvl];
    int ngroups = (M + 3) >> 2;
    int wid = threadIdx.x >> 6, lane = threadIdx.x & 63;
    for (int g = blockIdx.x; g < ngroups; g += gridDim.x) {
        int ni = g * 4 + wid;
        if (ni >= M) continue;
        int node = order[ni];
        int beg = offs[node], end = offs[node + 1];
        float ax = 0.f, ay = 0.f;
        for (int j = beg; j < end; ++j) {
            int s = csr[j];
            float2 v = *(const float2*)(H + (size_t)s * HD + lane * 2);
            ax += v.x; ay += v.y;
        }
        int c = cnt[node];
        float inv = 1.0f / (float)(c > 1 ? c : 1);
        *(float2*)(Out + (size_t)node * HD + lane * 2) = make_float2(ax * inv, ay * inv);
    }
}

// ---------------- fp32 tiled GEMM over node list (grid-stride) ----------------

#define GBM 64
#define GBK 32

__global__ __launch_bounds__(256) void gemm_list(
    const float* __restrict__ A1, const float* __restrict__ A2,
    const float* __restrict__ W1, const float* __restrict__ W2,
    const float* __restrict__ bias, float* __restrict__ Out,
    const int* __restrict__ order, const int* __restrict__ gather,
    const int* __restrict__ cumptr, int lvl, int do_relu) {

    __shared__ __align__(16) float As[GBK][68];
    __shared__ __align__(16) float Ws[GBK][132];

    int M = cumptr[lvl];
    int ntiles = (M + GBM - 1) / GBM;
    int tid = threadIdx.x;
    int tx = tid & 15, ty = tid >> 4;
    int r0 = ty * 4;
    int c0 = tx * 4;
    int nchunk = A2 ? 8 : 4;

    for (int tile = blockIdx.x; tile < ntiles; tile += gridDim.x) {
        int row0 = tile * GBM;

        float acc[4][8];
#pragma unroll
        for (int i = 0; i < 4; ++i)
#pragma unroll
            for (int j = 0; j < 8; ++j) acc[i][j] = 0.f;

        for (int ch = 0; ch < nchunk; ++ch) {
            const float* Asrc = (ch < 4) ? A1 : A2;
            const float* Wsrc = (ch < 4) ? W1 : W2;
            int kbase = (ch & 3) * GBK;

#pragma unroll
            for (int it = 0; it < 2; ++it) {
                int idx = tid + it * 256;
                int m = idx >> 3, kq = idx & 7;
                int row = row0 + m;
                float4 v = make_float4(0.f, 0.f, 0.f, 0.f);
                if (row < M) {
                    int nr = order[row];
                    int ar = gather ? gather[nr] : nr;
                    v = *(const float4*)(Asrc + (size_t)ar * 128 + kbase + kq * 4);
                }
                As[kq * 4 + 0][m] = v.x;
                As[kq * 4 + 1][m] = v.y;
                As[kq * 4 + 2][m] = v.z;
                As[kq * 4 + 3][m] = v.w;
            }
#pragma unroll
            for (int it = 0; it < 4; ++it) {
                int idx = tid + it * 256;
                int n = idx >> 3, kq = idx & 7;
                float4 v = *(const float4*)(Wsrc + n * 128 + kbase + kq * 4);
                Ws[kq * 4 + 0][n] = v.x;
                Ws[kq * 4 + 1][n] = v.y;
                Ws[kq * 4 + 2][n] = v.z;
                Ws[kq * 4 + 3][n] = v.w;
            }
            __syncthreads();

#pragma unroll
            for (int kk = 0; kk < GBK; ++kk) {
                float4 a  = *(const float4*)&As[kk][r0];
                float4 w0 = *(const float4*)&Ws[kk][c0];
                float4 w1 = *(const float4*)&Ws[kk][c0 + 64];
                float av[4] = {a.x, a.y, a.z, a.w};
                float wv[8] = {w0.x, w0.y, w0.z, w0.w, w1.x, w1.y, w1.z, w1.w};
#pragma unroll
                for (int i = 0; i < 4; ++i)
#pragma unroll
                    for (int j = 0; j < 8; ++j)
                        acc[i][j] = fmaf(av[i], wv[j], acc[i][j]);
            }
            __syncthreads();
        }

#pragma unroll
        for (int i = 0; i < 4; ++i) {
            int row = row0 + r0 + i;
            if (row >= M) continue;
            int nr = order[row];
            float4 o0, o1;
            o0.x = acc[i][0] + bias[c0 + 0];
            o0.y = acc[i][1] + bias[c0 + 1];
            o0.z = acc[i][2] + bias[c0 + 2];
            o0.w = acc[i][3] + bias[c0 + 3];
            o1.x = acc[i][4] + bias[c0 + 64];
            o1.y = acc[i][5] + bias[c0 + 65];
            o1.z = acc[i][6] + bias[c0 + 66];
            o1.w = acc[i][7] + bias[c0 + 67];
            if (do_relu) {
                o0.x = fmaxf(o0.x, 0.f); o0.y = fmaxf(o0.y, 0.f);
                o0.z = fmaxf(o0.z, 0.f); o0.w = fmaxf(o0.w, 0.f);
                o1.x = fmaxf(o1.x, 0.f); o1.y = fmaxf(o1.y, 0.f);
                o1.z = fmaxf(o1.z, 0.f); o1.w = fmaxf(o1.w, 0.f);
            }
            *(float4*)(Out + (size_t)nr * 128 + c0) = o0;
            *(float4*)(Out + (size_t)nr * 128 + c0 + 64) = o1;
        }
    }
}

// ---------------- head MLP on nodes 0,1 (coalesced GEMV) ----------------

__global__ __launch_bounds__(256) void head_kernel(
    const float* __restrict__ H,
    const float* __restrict__ W_e1, const float* __restrict__ b_e1,
    const float* __restrict__ W_e2, const float* __restrict__ b_e2,
    const float* __restrict__ W_h1, const float* __restrict__ b_h1,
    const float* __restrict__ W_h2, const float* __restrict__ b_h2,
    float* __restrict__ head_out, int kidx) {

    __shared__ float feat[384];   // [hu, hv, hu*hv]
    __shared__ float rowo[128];
    __shared__ float sc_sh;
    int t = threadIdx.x, lane = t & 63, wv = t >> 6;

    if (t < 128) {
        float a = H[t], b = H[128 + t];
        feat[t] = a;
        feat[128 + t] = b;
        feat[256 + t] = a * b;
    }
    __syncthreads();

    // e1: rows r in [0,128), wave per row, lanes over columns
    for (int r = wv; r < 128; r += 4) {
        const float* wr = W_e1 + r * 384;
        float acc = 0.f;
#pragma unroll
        for (int j = 0; j < 6; ++j)
            acc += feat[lane + 64 * j] * wr[lane + 64 * j];
        for (int off = 32; off; off >>= 1) acc += __shfl_down(acc, off);
        if (lane == 0) rowo[r] = fmaxf(acc + b_e1[r], 0.f) * W_e2[r];
    }
    __syncthreads();
    if (wv == 0) {
        float v = rowo[lane] + rowo[lane + 64];
        for (int off = 32; off; off >>= 1) v += __shfl_down(v, off);
        if (lane == 0) sc_sh = v + b_e2[0];
    }
    __syncthreads();
    float score = sc_sh;

    // h1: rows r in [0,64), hin = [hu, hv, score]
    for (int r = wv; r < 64; r += 4) {
        const float* wh = W_h1 + r * 257;
        float acc = 0.f;
#pragma unroll
        for (int j = 0; j < 4; ++j)
            acc += feat[lane + 64 * j] * wh[lane + 64 * j];
        if (lane == 0) acc += score * wh[256];
        for (int off = 32; off; off >>= 1) acc += __shfl_down(acc, off);
        if (lane == 0) rowo[r] = fmaxf(acc + b_h1[r], 0.f) * W_h2[r];
    }
    __syncthreads();
    if (wv == 0) {
        float v = rowo[lane];
        for (int off = 32; off; off >>= 1) v += __shfl_down(v, off);
        if (lane == 0) {
            float p = 1.f / (1.f + expf(-(v + b_h2[0])));
            head_out[kidx * 2 + 0] = score;
            head_out[kidx * 2 + 1] = p;
        }
    }
}

__global__ void finalize(const float* __restrict__ head_out, float* __restrict__ out) {
    if (threadIdx.x == 0 && blockIdx.x == 0) {
        float a[LMAX];
        float p_not = 1.f, s = 0.f;
        for (int k = 0; k < LMAX; ++k) {
            float p = head_out[2 * k + 1];
            a[k] = p * p_not;
            p_not *= (1.f - p);
            s += a[k];
        }
        float inv = 1.f / (s + 1e-8f);
        float fs = 0.f, ed = 0.f;
        for (int k = 0; k < LMAX; ++k) {
            float al = a[k] * inv;
            out[2 + k] = al;
            fs += al * head_out[2 * k];
            ed += al * (float)(k + 1);
        }
        out[0] = fs;
        out[1] = ed;
    }
}

// ---------------- launch ----------------

extern "C" void kernel_launch(void* const* d_in, const int* in_sizes, int n_in,
                              void* d_out, int out_size, void* d_ws, size_t ws_size,
                              hipStream_t stream) {
    const float* x_full = (const float*)d_in[0];
    const float* W_in  = (const float*)d_in[1];
    const float* b_in  = (const float*)d_in[2];
    const float* W_l   = (const float*)d_in[3];
    const float* b_l   = (const float*)d_in[4];
    const float* W_r   = (const float*)d_in[5];
    const float* W_e1  = (const float*)d_in[6];
    const float* b_e1  = (const float*)d_in[7];
    const float* W_e2  = (const float*)d_in[8];
    const float* b_e2  = (const float*)d_in[9];
    const float* W_h1  = (const float*)d_in[10];
    const float* b_h1  = (const float*)d_in[11];
    const float* W_h2  = (const float*)d_in[12];
    const float* b_h2  = (const float*)d_in[13];
    const int* subset  = (const int*)d_in[14];
    const int* edge    = (const int*)d_in[15];
    const int* esrc = edge;
    const int* edst = edge + E_NUM;

    // workspace carve-up
    char* w = (char*)d_ws;
    float* HA = (float*)w;      w += (size_t)N_SUB * HD * 4;   // 40.96 MB
    float* HB = (float*)w;      w += (size_t)N_SUB * HD * 4;   // 40.96 MB
    int* cnt = (int*)w;         w += (size_t)N_SUB * 4;
    int* offs = (int*)w;        w += (size_t)(N_SUB + 64) * 4;
    int* cursor = (int*)w;      w += (size_t)N_SUB * 4;
    int* csr = (int*)w;         w += (size_t)E_NUM * 4;        // 3.2 MB
    int* level = (int*)w;       w += (size_t)N_SUB * 4;
    int* order = (int*)w;       w += (size_t)N_SUB * 4;
    int* bsums = (int*)w;       w += 4096;
    int* bhist = (int*)w;       w += (size_t)(NB_SCAN + 1) * 8 * 4;
    int* lvlbase = (int*)w;     w += 64;
    int* cum = (int*)w;         w += 64;
    float* head_out = (float*)w; w += 256;

    // init + CSR build
    init_all<<<NB_SCAN, 256, 0, stream>>>(cnt, cursor, level);
    count_deg<<<(E_NUM + 255) / 256, 256, 0, stream>>>(edst, cnt);
    scan_block<<<NB_SCAN, 256, 0, stream>>>(cnt, offs, bsums);
    scan_sums<<<1, 512, 0, stream>>>(bsums);
    scan_add<<<NB_SCAN, 256, 0, stream>>>(offs, bsums);
    fill_csr<<<(E_NUM + 255) / 256, 256, 0, stream>>>(esrc, edst, offs, cursor, csr);

    // reverse BFS levels from {0,1}
    for (int t = 0; t < 5; ++t)
        bfs_pass<<<(E_NUM + 255) / 256, 256, 0, stream>>>(esrc, edst, level, t);

    // level compaction (atomic-free)
    hist_levels<<<NB_SCAN, 256, 0, stream>>>(level, bhist);
    scan_hist<<<1, 64, 0, stream>>>(bhist, lvlbase, cum);
    emit_order<<<NB_SCAN, 256, 0, stream>>>(level, bhist, lvlbase, order);

    // input projection on C_5: HA[nr] = x_full[subset[nr]] @ W_in.T + b_in
    gemm_list<<<1250, 256, 0, stream>>>(
        x_full, nullptr, W_in, nullptr, b_in, HA, order, subset, cum, 5, 0);

    for (int k = 1; k <= LMAX; ++k) {
        int lvl = LMAX - k;                   // compute on C_{5-k}
        int agrid  = (k == 1) ? 2048 : 96;
        int ggrid  = (k == 1) ? 640  : 96;
        aggregate_list<<<agrid, 256, 0, stream>>>(HA, HB, offs, csr, cnt, order, cum, lvl);
        gemm_list<<<ggrid, 256, 0, stream>>>(
            HB, HA, W_l, W_r, b_l, HA, order, nullptr, cum, lvl, 1);
        head_kernel<<<1, 256, 0, stream>>>(HA, W_e1, b_e1, W_e2, b_e2,
                                           W_h1, b_h1, W_h2, b_h2, head_out, k - 1);
    }
    finalize<<<1, 1, 0, stream>>>(head_out, (float*)d_out);
}

// Round 4
// 449.748 us; speedup vs baseline: 3.5639x; 1.0641x over previous
//
#include <hip/hip_runtime.h>
#include <hip/hip_bf16.h>

#define N_FULL 200000
#define N_SUB  80000
#define E_NUM  800000
#define IN_DIM 128
#define HD     128
#define LMAX   5

#define NB_SCAN ((N_SUB + 255) / 256)   // 313

// ---------------- init + CSR build ----------------

__global__ void init_all(int* __restrict__ cnt, int* __restrict__ cursor,
                         int* __restrict__ level) {
    int i = blockIdx.x * blockDim.x + threadIdx.x;
    if (i < N_SUB) {
        cnt[i] = 0;
        cursor[i] = 0;
        level[i] = (i < 2) ? 0 : 7;
    }
}

__global__ void count_deg(const int* __restrict__ dst, int* __restrict__ cnt) {
    int i = blockIdx.x * blockDim.x + threadIdx.x;
    if (i < E_NUM) atomicAdd(&cnt[dst[i]], 1);
}

__global__ void scan_block(const int* __restrict__ cnt, int* __restrict__ offs,
                           int* __restrict__ bsums) {
    __shared__ int s[256];
    int t = threadIdx.x;
    int i = blockIdx.x * 256 + t;
    int v = (i < N_SUB) ? cnt[i] : 0;
    s[t] = v;
    __syncthreads();
    for (int off = 1; off < 256; off <<= 1) {
        int x = (t >= off) ? s[t - off] : 0;
        __syncthreads();
        s[t] += x;
        __syncthreads();
    }
    if (i < N_SUB) offs[i] = s[t] - v;
    if (t == 255) bsums[blockIdx.x] = s[255];
}

__global__ void scan_sums(int* __restrict__ bsums) {
    __shared__ int s[512];
    int t = threadIdx.x;
    int v = (t < NB_SCAN) ? bsums[t] : 0;
    s[t] = v;
    __syncthreads();
    for (int off = 1; off < 512; off <<= 1) {
        int x = (t >= off) ? s[t - off] : 0;
        __syncthreads();
        s[t] += x;
        __syncthreads();
    }
    if (t < NB_SCAN) bsums[t] = s[t] - v;
}

__global__ void scan_add(int* __restrict__ offs, const int* __restrict__ bsums) {
    int i = blockIdx.x * 256 + threadIdx.x;
    if (i < N_SUB) offs[i] += bsums[blockIdx.x];
    if (i == 0) offs[N_SUB] = E_NUM;
}

__global__ void fill_csr(const int* __restrict__ src, const int* __restrict__ dst,
                         const int* __restrict__ offs, int* __restrict__ cursor,
                         int* __restrict__ csr) {
    int i = blockIdx.x * blockDim.x + threadIdx.x;
    if (i < E_NUM) {
        int d = dst[i];
        int p = atomicAdd(&cursor[d], 1);
        csr[offs[d] + p] = src[i];
    }
}

// ---------------- reverse BFS from {0,1} via CSR (frontier-sparse) ----------------
// pass t: nodes v with level[v]==t walk their in-edges; level[u] <- t+1 if unvisited.
// Benign race: all writers in a pass write the same value t+1.

__global__ void bfs_csr(const int* __restrict__ offs, const int* __restrict__ csr,
                        int* __restrict__ level, int t) {
    int i = blockIdx.x * blockDim.x + threadIdx.x;
    if (i >= N_SUB) return;
    if (level[i] != t) return;
    int beg = offs[i], end = offs[i + 1];
    for (int j = beg; j < end; ++j) {
        int u = csr[j];
        if (level[u] > t + 1) level[u] = t + 1;
    }
}

// ---------------- level compaction (no global atomics) ----------------

__global__ __launch_bounds__(256) void hist_levels(const int* __restrict__ level,
                                                   int* __restrict__ bhist) {
    __shared__ int h[8];
    int t = threadIdx.x;
    if (t < 8) h[t] = 0;
    __syncthreads();
    int i = blockIdx.x * 256 + t;
    if (i < N_SUB) {
        int l = level[i];
        if (l > 5) l = 6;
        atomicAdd(&h[l], 1);   // LDS atomic, per-block only
    }
    __syncthreads();
    if (t < 8) bhist[blockIdx.x * 8 + t] = h[t];
}

__global__ void scan_hist(int* __restrict__ bhist, int* __restrict__ base,
                          int* __restrict__ cum) {
    __shared__ int tot[8];
    int t = threadIdx.x;
    if (t < 8) {
        int acc = 0;
        for (int b = 0; b < NB_SCAN; ++b) {
            int v = bhist[b * 8 + t];
            bhist[b * 8 + t] = acc;
            acc += v;
        }
        tot[t] = acc;
    }
    __syncthreads();
    if (t == 0) {
        int acc = 0;
        for (int l = 0; l <= 5; ++l) {
            base[l] = acc;
            acc += tot[l];
            cum[l] = acc;
        }
    }
}

__global__ __launch_bounds__(256) void emit_order(const int* __restrict__ level,
                                                  const int* __restrict__ bhist,
                                                  const int* __restrict__ base,
                                                  int* __restrict__ order) {
    __shared__ int woff[4][8];
    int t = threadIdx.x;
    int lane = t & 63, wv = t >> 6;
    int i = blockIdx.x * 256 + t;
    int l = 7;
    if (i < N_SUB) {
        l = level[i];
        if (l > 5) l = 6;
    }
    unsigned long long mybal = 0;
#pragma unroll
    for (int q = 0; q < 8; ++q) {
        unsigned long long b = __ballot(l == q);
        if (q == l) mybal = b;
        if (lane == 0) woff[wv][q] = (int)__popcll(b);
    }
    int inrank = (int)__popcll(mybal & ((1ull << lane) - 1ull));
    __syncthreads();
    if (t < 8) {
        int acc = 0;
        for (int w2 = 0; w2 < 4; ++w2) {
            int c = woff[w2][t];
            woff[w2][t] = acc;
            acc += c;
        }
    }
    __syncthreads();
    if (i < N_SUB && l <= 5) {
        int pos = base[l] + bhist[blockIdx.x * 8 + l] + woff[wv][l] + inrank;
        order[pos] = i;
    }
}

// ---------------- combined weights: Wc1 = W_l@W_in, Wc2 = W_r@W_in ----------------
// bc = W_l@b_in + W_r@b_in + b_l

__global__ __launch_bounds__(256) void wcomb(
    const float* __restrict__ W_l, const float* __restrict__ W_r,
    const float* __restrict__ W_in, const float* __restrict__ b_in,
    const float* __restrict__ b_l, float* __restrict__ Wc1,
    float* __restrict__ Wc2, float* __restrict__ bc) {
    int f = blockIdx.x;            // output row 0..127
    int t = threadIdx.x;           // 256
    int c = t & 127, p = t >> 7;   // p=0 -> Wc1 (W_l), p=1 -> Wc2 (W_r)
    __shared__ float wl[128], wr[128];
    if (t < 128) wl[t] = W_l[f * 128 + t];
    else wr[t - 128] = W_r[f * 128 + (t - 128)];
    __syncthreads();
    const float* wrow = p ? wr : wl;
    float acc = 0.f;
#pragma unroll 8
    for (int j = 0; j < 128; ++j)
        acc = fmaf(wrow[j], W_in[j * 128 + c], acc);
    (p ? Wc2 : Wc1)[f * 128 + c] = acc;
    if (t < 64) {
        float pa = (wl[t] + wr[t]) * b_in[t] + (wl[t + 64] + wr[t + 64]) * b_in[t + 64];
        for (int off = 32; off; off >>= 1) pa += __shfl_down(pa, off);
        if (t == 0) bc[f] = pa + b_l[f];
    }
}

// ---------------- mean aggregation over node list ----------------
// Per-edge source row: r = srcmap ? srcmap[csr[j]] : csr[j]; reads H[r][:].

__global__ __launch_bounds__(256) void aggregate_list(
    const float* __restrict__ H, float* __restrict__ Out,
    const int* __restrict__ offs, const int* __restrict__ csr,
    const int* __restrict__ cnt, const int* __restrict__ order,
    const int* __restrict__ cumptr, int lvl, const int* __restrict__ srcmap) {
    int M = cumptr[lvl];
    int ngroups = (M + 3) >> 2;
    int wid = threadIdx.x >> 6, lane = threadIdx.x & 63;
    for (int g = blockIdx.x; g < ngroups; g += gridDim.x) {
        int ni = g * 4 + wid;
        if (ni >= M) continue;
        int node = order[ni];
        int beg = offs[node], end = offs[node + 1];
        float ax = 0.f, ay = 0.f, bx = 0.f, by = 0.f;
        int j = beg;
        for (; j + 1 < end; j += 2) {
            int s0 = csr[j], s1 = csr[j + 1];
            int r0 = srcmap ? srcmap[s0] : s0;
            int r1 = srcmap ? srcmap[s1] : s1;
            float2 v0 = *(const float2*)(H + (size_t)r0 * HD + lane * 2);
            float2 v1 = *(const float2*)(H + (size_t)r1 * HD + lane * 2);
            ax += v0.x; ay += v0.y;
            bx += v1.x; by += v1.y;
        }
        if (j < end) {
            int s0 = csr[j];
            int r0 = srcmap ? srcmap[s0] : s0;
            float2 v0 = *(const float2*)(H + (size_t)r0 * HD + lane * 2);
            ax += v0.x; ay += v0.y;
        }
        int c = cnt[node];
        float inv = 1.0f / (float)(c > 1 ? c : 1);
        *(float2*)(Out + (size_t)node * HD + lane * 2) =
            make_float2((ax + bx) * inv, (ay + by) * inv);
    }
}

// ---------------- fp32 tiled GEMM over node list (grid-stride) ----------------
// rows i < M = cumptr[lvl]: nr = order[i]
// A1 row = gatherA ? gatherA[nr] : nr ; A2 row = gatherB ? gatherB[nr] : nr
// Out[nr][:] = act( A1r @ W1.T (+ A2r @ W2.T) + bias )

#define GBM 64
#define GBK 32

__global__ __launch_bounds__(256) void gemm_list(
    const float* __restrict__ A1, const float* __restrict__ A2,
    const float* __restrict__ W1, const float* __restrict__ W2,
    const float* __restrict__ bias, float* __restrict__ Out,
    const int* __restrict__ order, const int* __restrict__ gatherA,
    const int* __restrict__ gatherB, const int* __restrict__ cumptr,
    int lvl, int do_relu) {

    __shared__ __align__(16) float As[GBK][68];
    __shared__ __align__(16) float Ws[GBK][132];

    int M = cumptr[lvl];
    int ntiles = (M + GBM - 1) / GBM;
    int tid = threadIdx.x;
    int tx = tid & 15, ty = tid >> 4;
    int r0 = ty * 4;
    int c0 = tx * 4;
    int nchunk = A2 ? 8 : 4;

    for (int tile = blockIdx.x; tile < ntiles; tile += gridDim.x) {
        int row0 = tile * GBM;

        float acc[4][8];
#pragma unroll
        for (int i = 0; i < 4; ++i)
#pragma unroll
            for (int j = 0; j < 8; ++j) acc[i][j] = 0.f;

        for (int ch = 0; ch < nchunk; ++ch) {
            const float* Asrc = (ch < 4) ? A1 : A2;
            const float* Wsrc = (ch < 4) ? W1 : W2;
            const int* gmap = (ch < 4) ? gatherA : gatherB;
            int kbase = (ch & 3) * GBK;

#pragma unroll
            for (int it = 0; it < 2; ++it) {
                int idx = tid + it * 256;
                int m = idx >> 3, kq = idx & 7;
                int row = row0 + m;
                float4 v = make_float4(0.f, 0.f, 0.f, 0.f);
                if (row < M) {
                    int nr = order[row];
                    int ar = gmap ? gmap[nr] : nr;
                    v = *(const float4*)(Asrc + (size_t)ar * 128 + kbase + kq * 4);
                }
                As[kq * 4 + 0][m] = v.x;
                As[kq * 4 + 1][m] = v.y;
                As[kq * 4 + 2][m] = v.z;
                As[kq * 4 + 3][m] = v.w;
            }
#pragma unroll
            for (int it = 0; it < 4; ++it) {
                int idx = tid + it * 256;
                int n = idx >> 3, kq = idx & 7;
                float4 v = *(const float4*)(Wsrc + n * 128 + kbase + kq * 4);
                Ws[kq * 4 + 0][n] = v.x;
                Ws[kq * 4 + 1][n] = v.y;
                Ws[kq * 4 + 2][n] = v.z;
                Ws[kq * 4 + 3][n] = v.w;
            }
            __syncthreads();

#pragma unroll
            for (int kk = 0; kk < GBK; ++kk) {
                float4 a  = *(const float4*)&As[kk][r0];
                float4 w0 = *(const float4*)&Ws[kk][c0];
                float4 w1 = *(const float4*)&Ws[kk][c0 + 64];
                float av[4] = {a.x, a.y, a.z, a.w};
                float wv[8] = {w0.x, w0.y, w0.z, w0.w, w1.x, w1.y, w1.z, w1.w};
#pragma unroll
                for (int i = 0; i < 4; ++i)
#pragma unroll
                    for (int j = 0; j < 8; ++j)
                        acc[i][j] = fmaf(av[i], wv[j], acc[i][j]);
            }
            __syncthreads();
        }

#pragma unroll
        for (int i = 0; i < 4; ++i) {
            int row = row0 + r0 + i;
            if (row >= M) continue;
            int nr = order[row];
            float4 o0, o1;
            o0.x = acc[i][0] + bias[c0 + 0];
            o0.y = acc[i][1] + bias[c0 + 1];
            o0.z = acc[i][2] + bias[c0 + 2];
            o0.w = acc[i][3] + bias[c0 + 3];
            o1.x = acc[i][4] + bias[c0 + 64];
            o1.y = acc[i][5] + bias[c0 + 65];
            o1.z = acc[i][6] + bias[c0 + 66];
            o1.w = acc[i][7] + bias[c0 + 67];
            if (do_relu) {
                o0.x = fmaxf(o0.x, 0.f); o0.y = fmaxf(o0.y, 0.f);
                o0.z = fmaxf(o0.z, 0.f); o0.w = fmaxf(o0.w, 0.f);
                o1.x = fmaxf(o1.x, 0.f); o1.y = fmaxf(o1.y, 0.f);
                o1.z = fmaxf(o1.z, 0.f); o1.w = fmaxf(o1.w, 0.f);
            }
            *(float4*)(Out + (size_t)nr * 128 + c0) = o0;
            *(float4*)(Out + (size_t)nr * 128 + c0 + 64) = o1;
        }
    }
}

// ---------------- head MLP on nodes 0,1 (coalesced GEMV) ----------------

__global__ __launch_bounds__(256) void head_kernel(
    const float* __restrict__ H,
    const float* __restrict__ W_e1, const float* __restrict__ b_e1,
    const float* __restrict__ W_e2, const float* __restrict__ b_e2,
    const float* __restrict__ W_h1, const float* __restrict__ b_h1,
    const float* __restrict__ W_h2, const float* __restrict__ b_h2,
    float* __restrict__ head_out, int kidx) {

    __shared__ float feat[384];   // [hu, hv, hu*hv]
    __shared__ float rowo[128];
    __shared__ float sc_sh;
    int t = threadIdx.x, lane = t & 63, wv = t >> 6;

    if (t < 128) {
        float a = H[t], b = H[128 + t];
        feat[t] = a;
        feat[128 + t] = b;
        feat[256 + t] = a * b;
    }
    __syncthreads();

    for (int r = wv; r < 128; r += 4) {
        const float* wr = W_e1 + r * 384;
        float acc = 0.f;
#pragma unroll
        for (int j = 0; j < 6; ++j)
            acc += feat[lane + 64 * j] * wr[lane + 64 * j];
        for (int off = 32; off; off >>= 1) acc += __shfl_down(acc, off);
        if (lane == 0) rowo[r] = fmaxf(acc + b_e1[r], 0.f) * W_e2[r];
    }
    __syncthreads();
    if (wv == 0) {
        float v = rowo[lane] + rowo[lane + 64];
        for (int off = 32; off; off >>= 1) v += __shfl_down(v, off);
        if (lane == 0) sc_sh = v + b_e2[0];
    }
    __syncthreads();
    float score = sc_sh;

    for (int r = wv; r < 64; r += 4) {
        const float* wh = W_h1 + r * 257;
        float acc = 0.f;
#pragma unroll
        for (int j = 0; j < 4; ++j)
            acc += feat[lane + 64 * j] * wh[lane + 64 * j];
        if (lane == 0) acc += score * wh[256];
        for (int off = 32; off; off >>= 1) acc += __shfl_down(acc, off);
        if (lane == 0) rowo[r] = fmaxf(acc + b_h1[r], 0.f) * W_h2[r];
    }
    __syncthreads();
    if (wv == 0) {
        float v = rowo[lane];
        for (int off = 32; off; off >>= 1) v += __shfl_down(v, off);
        if (lane == 0) {
            float p = 1.f / (1.f + expf(-(v + b_h2[0])));
            head_out[kidx * 2 + 0] = score;
            head_out[kidx * 2 + 1] = p;
        }
    }
}

__global__ void finalize(const float* __restrict__ head_out, float* __restrict__ out) {
    if (threadIdx.x == 0 && blockIdx.x == 0) {
        float a[LMAX];
        float p_not = 1.f, s = 0.f;
        for (int k = 0; k < LMAX; ++k) {
            float p = head_out[2 * k + 1];
            a[k] = p * p_not;
            p_not *= (1.f - p);
            s += a[k];
        }
        float inv = 1.f / (s + 1e-8f);
        float fs = 0.f, ed = 0.f;
        for (int k = 0; k < LMAX; ++k) {
            float al = a[k] * inv;
            out[2 + k] = al;
            fs += al * head_out[2 * k];
            ed += al * (float)(k + 1);
        }
        out[0] = fs;
        out[1] = ed;
    }
}

// ---------------- launch ----------------

extern "C" void kernel_launch(void* const* d_in, const int* in_sizes, int n_in,
                              void* d_out, int out_size, void* d_ws, size_t ws_size,
                              hipStream_t stream) {
    const float* x_full = (const float*)d_in[0];
    const float* W_in  = (const float*)d_in[1];
    const float* b_in  = (const float*)d_in[2];
    const float* W_l   = (const float*)d_in[3];
    const float* b_l   = (const float*)d_in[4];
    const float* W_r   = (const float*)d_in[5];
    const float* W_e1  = (const float*)d_in[6];
    const float* b_e1  = (const float*)d_in[7];
    const float* W_e2  = (const float*)d_in[8];
    const float* b_e2  = (const float*)d_in[9];
    const float* W_h1  = (const float*)d_in[10];
    const float* b_h1  = (const float*)d_in[11];
    const float* W_h2  = (const float*)d_in[12];
    const float* b_h2  = (const float*)d_in[13];
    const int* subset  = (const int*)d_in[14];
    const int* edge    = (const int*)d_in[15];
    const int* esrc = edge;
    const int* edst = edge + E_NUM;

    // workspace carve-up
    char* w = (char*)d_ws;
    float* HA = (float*)w;      w += (size_t)N_SUB * HD * 4;   // 40.96 MB
    float* HB = (float*)w;      w += (size_t)N_SUB * HD * 4;   // 40.96 MB
    int* cnt = (int*)w;         w += (size_t)N_SUB * 4;
    int* offs = (int*)w;        w += (size_t)(N_SUB + 64) * 4;
    int* cursor = (int*)w;      w += (size_t)N_SUB * 4;
    int* csr = (int*)w;         w += (size_t)E_NUM * 4;        // 3.2 MB
    int* level = (int*)w;       w += (size_t)N_SUB * 4;
    int* order = (int*)w;       w += (size_t)N_SUB * 4;
    int* bsums = (int*)w;       w += 4096;
    int* bhist = (int*)w;       w += (size_t)(NB_SCAN + 1) * 8 * 4;
    int* lvlbase = (int*)w;     w += 64;
    int* cum = (int*)w;         w += 64;
    float* Wc1 = (float*)w;     w += 128 * 128 * 4;
    float* Wc2 = (float*)w;     w += 128 * 128 * 4;
    float* bc = (float*)w;      w += 512;
    float* head_out = (float*)w; w += 256;

    // init + CSR build
    init_all<<<NB_SCAN, 256, 0, stream>>>(cnt, cursor, level);
    count_deg<<<(E_NUM + 255) / 256, 256, 0, stream>>>(edst, cnt);
    scan_block<<<NB_SCAN, 256, 0, stream>>>(cnt, offs, bsums);
    scan_sums<<<1, 512, 0, stream>>>(bsums);
    scan_add<<<NB_SCAN, 256, 0, stream>>>(offs, bsums);
    fill_csr<<<(E_NUM + 255) / 256, 256, 0, stream>>>(esrc, edst, offs, cursor, csr);

    // combined weights (independent of graph work; enqueue early)
    wcomb<<<128, 256, 0, stream>>>(W_l, W_r, W_in, b_in, b_l, Wc1, Wc2, bc);

    // reverse BFS levels 1..4 from {0,1} via CSR (frontier-sparse)
    for (int t = 0; t < 4; ++t)
        bfs_csr<<<NB_SCAN, 256, 0, stream>>>(offs, csr, level, t);

    // level compaction (atomic-free)
    hist_levels<<<NB_SCAN, 256, 0, stream>>>(level, bhist);
    scan_hist<<<1, 64, 0, stream>>>(bhist, lvlbase, cum);
    emit_order<<<NB_SCAN, 256, 0, stream>>>(level, bhist, lvlbase, order);

    // step 1 on C_4 via linearity:
    // agg_x[v] = mean_{u in N(v)} x_full[subset[u]]
    // H1 = relu(agg_x @ Wc1.T + x_full[subset[v]] @ Wc2.T + bc)
    aggregate_list<<<2048, 256, 0, stream>>>(x_full, HB, offs, csr, cnt, order, cum, 4, subset);
    gemm_list<<<512, 256, 0, stream>>>(
        HB, x_full, Wc1, Wc2, bc, HA, order, nullptr, subset, cum, 4, 1);
    head_kernel<<<1, 256, 0, stream>>>(HA, W_e1, b_e1, W_e2, b_e2,
                                       W_h1, b_h1, W_h2, b_h2, head_out, 0);

    // steps 2..5 on C_3..C_0
    for (int k = 2; k <= LMAX; ++k) {
        int lvl = LMAX - k;
        aggregate_list<<<96, 256, 0, stream>>>(HA, HB, offs, csr, cnt, order, cum, lvl, nullptr);
        gemm_list<<<96, 256, 0, stream>>>(
            HB, HA, W_l, W_r, b_l, HA, order, nullptr, nullptr, cum, lvl, 1);
        head_kernel<<<1, 256, 0, stream>>>(HA, W_e1, b_e1, W_e2, b_e2,
                                           W_h1, b_h1, W_h2, b_h2, head_out, k - 1);
    }
    finalize<<<1, 1, 0, stream>>>(head_out, (float*)d_out);
}